// Round 9
// baseline (292.130 us; speedup 1.0000x reference)
//
#include <hip/hip_runtime.h>
#include <hip/hip_bf16.h>

#define N_NODES 50000
#define N_EDGES 800000
#define TOT_EDGES (N_EDGES + N_NODES)
#define IN_DIM 256
#define OUT_DIM 256   // HEADS * HID
#define HEADS 4
#define NEG_SLOPE 0.2f
#define MAXD 128      // LDS alpha-cache per node

#define GBLK 782      // gemm blocks: 64 rows each (50000 = 781*64 + 16)
#define FBLK 512      // fill blocks (run concurrently with gemm)
#define LDS_STRIDE 264  // 256 + 8 pad (bf16 elems)

typedef __bf16 bf16x8 __attribute__((ext_vector_type(8)));
typedef __bf16 bf16x4 __attribute__((ext_vector_type(4)));
typedef float f32x4 __attribute__((ext_vector_type(4)));

__device__ __forceinline__ float b2f(unsigned short u) {
    union { float f; unsigned int i; } v; v.i = ((unsigned int)u) << 16; return v.f;
}

// block-uniform int64-vs-int32 detection (all threads of block must call)
__device__ __forceinline__ bool detect64(const int* __restrict__ ei, int t) {
    int nz = 0;
    for (int i = t; i < 1024; i += 256)
        if (ei[2 * i + 1] != 0) nz++;
    return __syncthreads_count(nz) == 0;
}

struct Args {
    const float* x; const int* ei; const float* W;
    const float* att_s; const float* att_d; const float* bias;
    float* out;
    __bf16* Wt;   // swizzled: Wt[(k/32)*256 + n)*32 + k%32]
    __bf16* h; float* a_src; float* a_dst;
    int* counts; int* loc; int* bsum; int* bpref;
    int* offsets; int* cursor; int* csr_src; int* ticket;
};

// ---------------- K_front: swizzled W transpose + dst histogram -------------
// Wt2 layout gives fully-contiguous 1KB B-fragment loads in the gemm K-loop.
__global__ __launch_bounds__(256) void k_front(Args A) {
    if (blockIdx.x == 0 && threadIdx.x == 0) *A.ticket = 0;
    bool is64 = detect64(A.ei, threadIdx.x);
    int gid = blockIdx.x * 256 + threadIdx.x;
    int gsz = gridDim.x * 256;
    for (int i = gid; i < IN_DIM * OUT_DIM; i += gsz) {
        int n = i & 255, k = i >> 8;
        A.Wt[((size_t)(k >> 5) * 256 + n) * 32 + (k & 31)] = (__bf16)A.W[(size_t)k * OUT_DIM + n];
    }
    const long long* ei64 = (const long long*)A.ei;
    for (int i = gid; i < N_EDGES; i += gsz) {
        int v = is64 ? (int)ei64[N_EDGES + i] : A.ei[N_EDGES + i];
        atomicAdd(&A.counts[v], 1);
    }
}

// ---------------- K_scan_all: full prefix scan in ONE kernel ---------------
// 49 blocks local-scan; the last block to finish (device-scope ticket)
// scans the 49 block sums and writes offsets/cursor for all nodes.
#define SBLK 1024
#define NBLK ((N_NODES + SBLK - 1) / SBLK)   // 49
__global__ __launch_bounds__(1024) void k_scan_all(Args A) {
    __shared__ int s[SBLK];
    __shared__ int bp[64];
    __shared__ int lastflag;
    int t = threadIdx.x, idx = blockIdx.x * SBLK + t;
    int cval = (idx < N_NODES) ? A.counts[idx] + 1 : 0;   // +1 = self loop
    s[t] = cval;
    __syncthreads();
    for (int off = 1; off < SBLK; off <<= 1) {
        int v = (t >= off) ? s[t - off] : 0;
        __syncthreads();
        s[t] += v;
        __syncthreads();
    }
    if (idx < N_NODES) A.loc[idx] = s[t] - cval;
    if (t == SBLK - 1) A.bsum[blockIdx.x] = s[t];
    __threadfence();          // release loc/bsum writes (device scope)
    __syncthreads();
    if (t == 0) lastflag = (atomicAdd(A.ticket, 1) == NBLK - 1) ? 1 : 0;
    __syncthreads();
    if (!lastflag) return;
    __threadfence();          // acquire other blocks' writes
    if (t < 64) {
        int v = (t < NBLK) ? A.bsum[t] : 0;
        int orig = v;
#pragma unroll
        for (int off = 1; off < 64; off <<= 1) {
            int u = __shfl_up(v, off, 64);
            if (t >= off) v += u;
        }
        bp[t] = v - orig;
        if (t == 0) A.offsets[N_NODES] = TOT_EDGES;
    }
    __syncthreads();
    for (int i = t; i < N_NODES; i += SBLK) {
        int o = A.loc[i] + bp[i >> 10];
        A.offsets[i] = o;
        A.cursor[i] = o;
    }
}

// ---------------- K_gemm_fill: 64-row LDS GEMM || CSR fill ------------------
__global__ __launch_bounds__(256) void k_gemm_fill(Args A) {
    __shared__ __bf16 xs[64 * LDS_STRIDE];   // 33 KB
    const int t = threadIdx.x;

    if (blockIdx.x < GBLK) {
        // ---- stage x[mbase .. mbase+64) -> bf16 LDS (coalesced float4) ----
        const int mbase = blockIdx.x * 64;
        const float4* x4 = (const float4*)A.x;
#pragma unroll
        for (int i = 0; i < 16; ++i) {
            int f = i * 256 + t;
            int row = f >> 6;
            int c4  = f & 63;
            int grow = mbase + row;
            if (grow >= N_NODES) grow = N_NODES - 1;
            float4 v = x4[(size_t)grow * 64 + c4];
            bf16x4 o = { (__bf16)v.x, (__bf16)v.y, (__bf16)v.z, (__bf16)v.w };
            *(bf16x4*)&xs[row * LDS_STRIDE + c4 * 4] = o;
        }
        __syncthreads();

        const int wave = t >> 6;
        const int lane = t & 63;
        const int cc   = lane & 15;
        const int quad = lane >> 4;
        const int n0   = wave * 64;
        f32x4 acc[4][4];
#pragma unroll
        for (int mt = 0; mt < 4; ++mt)
#pragma unroll
            for (int j = 0; j < 4; ++j) acc[mt][j] = (f32x4){0.f, 0.f, 0.f, 0.f};

        for (int k0 = 0; k0 < IN_DIM; k0 += 32) {
            // swizzled layout: each load is 1KB contiguous across the wave
            const __bf16* wb = A.Wt + ((size_t)(k0 >> 5) * 256) * 32 + quad * 8;
            bf16x8 b0 = *(const bf16x8*)(wb + (size_t)(n0 + cc)      * 32);
            bf16x8 b1 = *(const bf16x8*)(wb + (size_t)(n0 + 16 + cc) * 32);
            bf16x8 b2 = *(const bf16x8*)(wb + (size_t)(n0 + 32 + cc) * 32);
            bf16x8 b3 = *(const bf16x8*)(wb + (size_t)(n0 + 48 + cc) * 32);
#pragma unroll
            for (int mt = 0; mt < 4; ++mt) {
                bf16x8 a = *(const bf16x8*)&xs[(mt * 16 + cc) * LDS_STRIDE + k0 + quad * 8];
                acc[mt][0] = __builtin_amdgcn_mfma_f32_16x16x32_bf16(a, b0, acc[mt][0], 0, 0, 0);
                acc[mt][1] = __builtin_amdgcn_mfma_f32_16x16x32_bf16(a, b1, acc[mt][1], 0, 0, 0);
                acc[mt][2] = __builtin_amdgcn_mfma_f32_16x16x32_bf16(a, b2, acc[mt][2], 0, 0, 0);
                acc[mt][3] = __builtin_amdgcn_mfma_f32_16x16x32_bf16(a, b3, acc[mt][3], 0, 0, 0);
            }
        }

        float as0 = A.att_s[n0 + cc],      as1 = A.att_s[n0 + 16 + cc];
        float as2 = A.att_s[n0 + 32 + cc], as3 = A.att_s[n0 + 48 + cc];
        float ad0 = A.att_d[n0 + cc],      ad1 = A.att_d[n0 + 16 + cc];
        float ad2 = A.att_d[n0 + 32 + cc], ad3 = A.att_d[n0 + 48 + cc];
#pragma unroll
        for (int mt = 0; mt < 4; ++mt) {
#pragma unroll
            for (int r = 0; r < 4; ++r) {
                int row = mbase + mt * 16 + quad * 4 + r;
                bool ok = row < N_NODES;
                float pS = acc[mt][0][r] * as0 + acc[mt][1][r] * as1
                         + acc[mt][2][r] * as2 + acc[mt][3][r] * as3;
                float pD = acc[mt][0][r] * ad0 + acc[mt][1][r] * ad1
                         + acc[mt][2][r] * ad2 + acc[mt][3][r] * ad3;
#pragma unroll
                for (int o = 8; o >= 1; o >>= 1) {
                    pS += __shfl_xor(pS, o, 64);
                    pD += __shfl_xor(pD, o, 64);
                }
                if (ok) {
                    __bf16* orow = A.h + (size_t)row * OUT_DIM + n0 + cc;
                    orow[0]  = (__bf16)acc[mt][0][r];
                    orow[16] = (__bf16)acc[mt][1][r];
                    orow[32] = (__bf16)acc[mt][2][r];
                    orow[48] = (__bf16)acc[mt][3][r];
                    if (cc == 0) {
                        A.a_src[row * 4 + wave] = pS;
                        A.a_dst[row * 4 + wave] = pD;
                    }
                }
            }
        }
    } else {
        // ---- CSR fill (independent of GEMM; cursor ready from k_scan_all) --
        bool is64 = detect64(A.ei, t);
        const long long* ei64 = (const long long*)A.ei;
        int bi = blockIdx.x - GBLK;
        for (int i = bi * 256 + t; i < TOT_EDGES; i += FBLK * 256) {
            if (i < N_EDGES) {
                int s, d;
                if (is64) { s = (int)ei64[i]; d = (int)ei64[N_EDGES + i]; }
                else      { s = A.ei[i];      d = A.ei[N_EDGES + i]; }
                int pos = atomicAdd(&A.cursor[d], 1);
                A.csr_src[pos] = s;
            } else {
                int n = i - N_EDGES;
                int pos = atomicAdd(&A.cursor[n], 1);
                A.csr_src[pos] = n;
            }
        }
    }
}

// ---------------- K_agg: 2-pass softmax (no max) + aggregation --------------
__global__ __launch_bounds__(256) void k_agg(Args A) {
    __shared__ float lds_all[4][MAXD][4];
    int wave = threadIdx.x >> 6, lane = threadIdx.x & 63;
    int node = blockIdx.x * 4 + wave;
    if (node >= N_NODES) return;
    float (*lds)[4] = lds_all[wave];

    int base = A.offsets[node];
    int deg  = A.offsets[node + 1] - base;
    const float4* as4 = (const float4*)A.a_src;
    float4 ad = ((const float4*)A.a_dst)[node];

    // pass A: alpha = exp(leaky(a_src+a_dst)) -> LDS, running sum
    // (max subtraction skipped: |logit| <= ~10 << 88, exp cannot overflow)
    float4 smv = {0.f, 0.f, 0.f, 0.f};
    for (int e = lane; e < deg; e += 64) {
        int s = A.csr_src[base + e];
        float4 av = as4[s];
        float4 l;
        l.x = av.x + ad.x; l.x = l.x > 0.f ? l.x : NEG_SLOPE * l.x;
        l.y = av.y + ad.y; l.y = l.y > 0.f ? l.y : NEG_SLOPE * l.y;
        l.z = av.z + ad.z; l.z = l.z > 0.f ? l.z : NEG_SLOPE * l.z;
        l.w = av.w + ad.w; l.w = l.w > 0.f ? l.w : NEG_SLOPE * l.w;
        float4 e4;
        e4.x = __expf(l.x); e4.y = __expf(l.y);
        e4.z = __expf(l.z); e4.w = __expf(l.w);
        smv.x += e4.x; smv.y += e4.y; smv.z += e4.z; smv.w += e4.w;
        if (e < MAXD) { lds[e][0] = e4.x; lds[e][1] = e4.y; lds[e][2] = e4.z; lds[e][3] = e4.w; }
    }
    int padEnd = (deg + 3) & ~3;
    if (padEnd > MAXD) padEnd = MAXD;
    for (int e = deg + lane; e < padEnd; e += 64) {
        lds[e][0] = 0.f; lds[e][1] = 0.f; lds[e][2] = 0.f; lds[e][3] = 0.f;
    }
#pragma unroll
    for (int o = 32; o >= 1; o >>= 1) {
        smv.x += __shfl_xor(smv.x, o, 64);
        smv.y += __shfl_xor(smv.y, o, 64);
        smv.z += __shfl_xor(smv.z, o, 64);
        smv.w += __shfl_xor(smv.w, o, 64);
    }

    int head = lane >> 4;
    float smh = head == 0 ? smv.x : head == 1 ? smv.y : head == 2 ? smv.z : smv.w;
    float adh = head == 0 ? ad.x  : head == 1 ? ad.y  : head == 2 ? ad.z  : ad.w;
    float inv_d = 1.f / smh;

    // pass B: unroll-by-4 gather + FMA (alpha from LDS)
    float acc0 = 0.f, acc1 = 0.f, acc2 = 0.f, acc3 = 0.f;
    const unsigned short* hs = reinterpret_cast<const unsigned short*>(A.h);
    int degc = deg < MAXD ? deg : MAXD;
    int rEnd = (degc + 3) & ~3;
    for (int e = 0; e < rEnd; e += 4) {
        int s0 = A.csr_src[base + e];
        int s1 = A.csr_src[base + ((e + 1 < deg) ? e + 1 : 0)];
        int s2 = A.csr_src[base + ((e + 2 < deg) ? e + 2 : 0)];
        int s3 = A.csr_src[base + ((e + 3 < deg) ? e + 3 : 0)];
        float al0 = lds[e][head];
        float al1 = lds[e + 1][head];
        float al2 = lds[e + 2][head];
        float al3 = lds[e + 3][head];
        ushort4 h0 = *(const ushort4*)(hs + (size_t)s0 * OUT_DIM + lane * 4);
        ushort4 h1 = *(const ushort4*)(hs + (size_t)s1 * OUT_DIM + lane * 4);
        ushort4 h2 = *(const ushort4*)(hs + (size_t)s2 * OUT_DIM + lane * 4);
        ushort4 h3 = *(const ushort4*)(hs + (size_t)s3 * OUT_DIM + lane * 4);
        acc0 += al0 * b2f(h0.x) + al1 * b2f(h1.x) + al2 * b2f(h2.x) + al3 * b2f(h3.x);
        acc1 += al0 * b2f(h0.y) + al1 * b2f(h1.y) + al2 * b2f(h2.y) + al3 * b2f(h3.y);
        acc2 += al0 * b2f(h0.z) + al1 * b2f(h1.z) + al2 * b2f(h2.z) + al3 * b2f(h3.z);
        acc3 += al0 * b2f(h0.w) + al1 * b2f(h1.w) + al2 * b2f(h2.w) + al3 * b2f(h3.w);
    }
    // rare tail: deg > MAXD -> recompute alpha
    for (int e = MAXD; e < deg; ++e) {
        int s = A.csr_src[base + e];
        float a = A.a_src[s * 4 + head] + adh;
        a = a > 0.f ? a : NEG_SLOPE * a;
        float al = __expf(a);
        ushort4 hv = *(const ushort4*)(hs + (size_t)s * OUT_DIM + lane * 4);
        acc0 += al * b2f(hv.x); acc1 += al * b2f(hv.y);
        acc2 += al * b2f(hv.z); acc3 += al * b2f(hv.w);
    }

    float4 bv = ((const float4*)A.bias)[lane];
    float v0 = acc0 * inv_d + bv.x;
    float v1 = acc1 * inv_d + bv.y;
    float v2 = acc2 * inv_d + bv.z;
    float v3 = acc3 * inv_d + bv.w;
    float4 o4;
    o4.x = v0 > 0.f ? v0 : 0.f;
    o4.y = v1 > 0.f ? v1 : 0.f;
    o4.z = v2 > 0.f ? v2 : 0.f;
    o4.w = v3 > 0.f ? v3 : 0.f;
    ((float4*)A.out)[(size_t)node * 64 + lane] = o4;
}

// ---------------------------------------------------------------------------
extern "C" void kernel_launch(void* const* d_in, const int* in_sizes, int n_in,
                              void* d_out, int out_size, void* d_ws, size_t ws_size,
                              hipStream_t stream) {
    (void)out_size; (void)ws_size;
    const void* p_x = nullptr; const void* p_ei = nullptr; const void* p_W = nullptr;
    const void* p_small[3] = {nullptr, nullptr, nullptr}; int nsmall = 0;
    for (int i = 0; i < n_in; ++i) {
        switch (in_sizes[i]) {
            case N_NODES * IN_DIM:      p_x = d_in[i]; break;
            case 2 * N_EDGES:           p_ei = d_in[i]; break;
            case IN_DIM * OUT_DIM:      p_W = d_in[i]; break;
            case OUT_DIM:               if (nsmall < 3) p_small[nsmall++] = d_in[i]; break;
            default: break;
        }
    }
    if (!p_x)  p_x  = d_in[0];
    if (!p_ei) p_ei = d_in[1];
    if (!p_W)  p_W  = d_in[2];
    if (nsmall < 3) { p_small[0] = d_in[3]; p_small[1] = d_in[4]; p_small[2] = d_in[5]; }

    char* ws = (char*)d_ws;
    size_t off = 0;
    auto alloc = [&](size_t bytes) -> void* {
        void* p = ws + off;
        off = (off + bytes + 255) & ~(size_t)255;
        return p;
    };
    Args A;
    A.Wt      = (__bf16*)alloc((size_t)IN_DIM * OUT_DIM * 2);
    A.h       = (__bf16*)alloc((size_t)N_NODES * OUT_DIM * 2);
    A.a_src   = (float*)alloc((size_t)N_NODES * HEADS * 4);
    A.a_dst   = (float*)alloc((size_t)N_NODES * HEADS * 4);
    A.counts  = (int*)alloc((size_t)N_NODES * 4);
    A.loc     = (int*)alloc((size_t)N_NODES * 4);
    A.bsum    = (int*)alloc(NBLK * 4);
    A.bpref   = (int*)alloc(NBLK * 4);
    A.offsets = (int*)alloc((size_t)(N_NODES + 1) * 4);
    A.cursor  = (int*)alloc((size_t)N_NODES * 4);
    A.csr_src = (int*)alloc((size_t)TOT_EDGES * 4);
    A.ticket  = (int*)alloc(4);

    A.x     = (const float*)p_x;
    A.ei    = (const int*)p_ei;
    A.W     = (const float*)p_W;
    A.att_s = (const float*)p_small[0];
    A.att_d = (const float*)p_small[1];
    A.bias  = (const float*)p_small[2];
    A.out   = (float*)d_out;

    hipMemsetAsync(A.counts, 0, (size_t)N_NODES * 4, stream);
    k_front<<<dim3(1024), dim3(256), 0, stream>>>(A);
    k_scan_all<<<dim3(NBLK), dim3(SBLK), 0, stream>>>(A);
    k_gemm_fill<<<dim3(GBLK + FBLK), dim3(256), 0, stream>>>(A);
    k_agg<<<dim3((N_NODES + 3) / 4), dim3(256), 0, stream>>>(A);
}